// Round 22
// baseline (47.998 us; speedup 1.0000x reference)
//
#include <hip/hip_runtime.h>

// Steered 3x3 conv as per-pixel GEMM (K=256 = 64ch x 4 feats) via bf16 MFMA.
// v22 = r16 (best, 36.6us) + ONLY the store-cut epilogue, isolated:
// r21's VMEM cut (140->60/unit) was confounded by LDS 74KB -> 2 blocks/CU.
// Here LDS stays 40960B (3 blocks/CU), weight prefetch stays in registers,
// pipeline identical to r16. Changes:
//  (a) epilogue: each 32x32 acc quadrant transposed through the dead wave-
//      private xs[W] buffer -> global_store_dwordx4; 64 -> 16 store instrs.
//      Lane -> plane olp=(lane>>3)*4+i, cols wq*4..+3 (16B aligned).
//  (b) bias preloaded as 2x dwordx4/lane at the HEAD of the VMEM queue
//      (oldest -> self-retires; phase-0 vmcnt(5) still retires s0+w0).
// Net ~92 VMEM instrs/unit vs 140. If flat, VMEM-instr model is dead.
// B-frag: lane l -> col = l&31 (pixel), k = 16*kcg + 8*(l>>5) + r (verified r2)
// C/D:    col = lane&31, row(o) = (r&3) + 8*(r>>2) + 4*(lane>>5)  (verified r2)

typedef __bf16 bf16x8 __attribute__((ext_vector_type(8)));
typedef float  f32x16 __attribute__((ext_vector_type(16)));
typedef float  f32x4  __attribute__((ext_vector_type(4)));
typedef float  f32x2  __attribute__((ext_vector_type(2)));
typedef unsigned int u32;
typedef const __attribute__((address_space(1))) u32* gp_t;
typedef __attribute__((address_space(3))) u32* lp_t;

#define HH 128
#define WW 128
#define HW 16384
#define CHIMG 65536          // bytes per (n,ch) plane

__device__ __forceinline__ f32x2 sp(float v) { return (f32x2){v, v}; }

// Weights f32[o][k] -> bf16, pre-scaled per feature and grouped per MFMA
// A-fragment: wb[((kcg*2+hx)*64 + o)*8 + r] = bf16(sc[k&3] * wt[o][k])
__global__ void wt_repack(const float* __restrict__ wt,
                          unsigned short* __restrict__ wb) {
    int i = blockIdx.x * 256 + threadIdx.x;   // i = o*256 + k
    int o = i >> 8, k = i & 255;
    const float sc[4] = {1.f, 0.35355339059327373f, 0.35355339059327373f, 0.5f};
    union { float f; u32 u; } v; v.f = wt[i] * sc[k & 3];
    unsigned short b = (unsigned short)((v.u + 0x7FFF + ((v.u >> 16) & 1)) >> 16);
    int kcg = k >> 4, hxx = (k >> 3) & 1, r = k & 7;
    wb[((kcg * 2 + hxx) * 64 + o) * 8 + r] = b;
}

__global__ __launch_bounds__(256, 3) void steered_conv_mfma(
    const float* __restrict__ x, const float* __restrict__ theta,
    const unsigned short* __restrict__ wb, const float* __restrict__ bias,
    float* __restrict__ out)
{
    // 4 wave-private staging slices: [wave][2 bufs][8 ch][4 rows][40 f32]
    __shared__ __attribute__((aligned(16))) float xs[4][2][8][4][40]; // 40960B

    const int tid  = threadIdx.x;
    const int W    = tid >> 6;
    const int lane = tid & 63;
    const int pc = lane & 31, hx = lane >> 5;

    // bijective XCD swizzle over 1024 blocks; block covers 4 wave-units
    const int bb   = blockIdx.x;
    const int swz  = (bb & 7) * 128 + (bb >> 3);
    const int unit = swz * 4 + W;
    const int n    = unit >> 8;
    const int rem  = unit & 255;
    const int hA   = (rem >> 2) * 2;    // wave's first pixel row (0..126)
    const int w0   = (rem & 3) * 32;
    const int w    = w0 + pc;

    // ---- bias preload: HEAD of the VMEM queue (oldest; self-retires) ----
    const int olp0 = (lane >> 3) * 4;   // this lane's o-plane base (epilogue)
    const f32x4 b4lo = *(const f32x4*)(bias + olp0);
    const f32x4 b4hi = *(const f32x4*)(bias + 32 + olp0);
    __builtin_amdgcn_sched_barrier(0);

    // ---- per-lane DMA offsets (-1 = skip): 5 x 1024B chunks / [8ch][4r][160B] ----
    int soff[5];
    #pragma unroll
    for (int d = 0; d < 5; ++d) {
        const int i   = d * 1024 + lane * 16;
        const int ch  = i / 640;
        const int rm  = i - ch * 640;
        const int row = rm / 160;
        const int c16 = rm - row * 160;
        const int gh  = hA - 1 + row;
        const int ghc = gh < 0 ? 0 : (gh > 127 ? 127 : gh);
        int so = ch * CHIMG + ghc * 512 + w0 * 4 - 16 + c16;
        so = so < 0 ? 0 : so;
        const bool sk = (gh < 0) | (gh > 127) |
                        ((w0 == 0) & (c16 < 16)) | ((w0 == 96) & (c16 >= 144));
        soff[d] = sk ? -1 : so;
    }

    const char* xn = (const char*)x + (size_t)n * 64 * CHIMG;

    // ---- theta + harmonics (VMEM retires before the pipeline) ----
    float s1a, c1a, s1b, c1b;
    __sincosf(6.2831853071795864769f * theta[(n*HH + hA)*WW + w], &s1a, &c1a);
    __sincosf(6.2831853071795864769f * theta[(n*HH + hA+1)*WW + w], &s1b, &c1b);
    const float c2a = 2.f*c1a*c1a - 1.f, s2a = 2.f*s1a*c1a;
    const float c2b = 2.f*c1b*c1b - 1.f, s2b = 2.f*s1b*c1b;

    // ---- pre-zero own bufs when any slot will be skipped (wave-local) ----
    if (hA == 0 || hA == 126 || w0 == 0 || w0 == 96) {
        f32x4* z = (f32x4*)&xs[W][0][0][0][0];
        #pragma unroll
        for (int i = 0; i < 10; ++i)
            z[lane + i * 64] = f32x4{0.f, 0.f, 0.f, 0.f};
        asm volatile("s_waitcnt lgkmcnt(0)" ::: "memory");
    }

    auto stage = [&](int t) {                  // stages channels t*8..t*8+7
        const char* sb = xn + (size_t)(t * 8) * CHIMG;
        char* db = (char*)&xs[W][t & 1][0][0][0];
        #pragma unroll
        for (int d = 0; d < 5; ++d)
            if (soff[d] >= 0)
                __builtin_amdgcn_global_load_lds((gp_t)(sb + soff[d]),
                                                 (lp_t)(db + d * 1024), 16, 0, 0);
    };

    const unsigned short* wbl = wb + (hx * 64 + pc) * 8;
    bf16x8 wE0, wE1, wE2, wE3, wO0, wO1, wO2, wO3;

    // prologue queue: [bias:2, s(0):5, w(0):4, s(1):5]
    stage(0);
    __builtin_amdgcn_sched_barrier(0);
    {
        const unsigned short* wr = wbl;
        wE0 = *(const bf16x8*)(wr);
        wE1 = *(const bf16x8*)(wr + 256);
        wE2 = *(const bf16x8*)(wr + 1024);
        wE3 = *(const bf16x8*)(wr + 1280);
    }
    __builtin_amdgcn_sched_barrier(0);
    stage(1);
    __builtin_amdgcn_sched_barrier(0);

    f32x16 acc00, acc01, acc10, acc11;
    #pragma unroll
    for (int r = 0; r < 16; ++r) { acc00[r]=0.f; acc01[r]=0.f; acc10[r]=0.f; acc11[r]=0.f; }

    #pragma unroll
    for (int c = 0; c < 8; ++c) {
        // retire s(c)+w(c) (+bias at c=0); leave s(c+1) in flight
        if (c == 7) asm volatile("s_waitcnt vmcnt(0)" ::: "memory");
        else        asm volatile("s_waitcnt vmcnt(5)" ::: "memory");
        __builtin_amdgcn_sched_barrier(0);
        if (c < 7) {   // weight prefetch for phase c+1 (before s(c+2))
            const unsigned short* wr = wbl + (c + 1) * 2048;
            if ((c + 1) & 1) {
                wO0 = *(const bf16x8*)(wr);
                wO1 = *(const bf16x8*)(wr + 256);
                wO2 = *(const bf16x8*)(wr + 1024);
                wO3 = *(const bf16x8*)(wr + 1280);
            } else {
                wE0 = *(const bf16x8*)(wr);
                wE1 = *(const bf16x8*)(wr + 256);
                wE2 = *(const bf16x8*)(wr + 1024);
                wE3 = *(const bf16x8*)(wr + 1280);
            }
            __builtin_amdgcn_sched_barrier(0);
        }

        const bf16x8 A00 = (c & 1) ? wO0 : wE0;
        const bf16x8 A01 = (c & 1) ? wO1 : wE1;
        const bf16x8 A10 = (c & 1) ? wO2 : wE2;
        const bf16x8 A11 = (c & 1) ? wO3 : wE3;

        const float* tb = &xs[W][c & 1][0][0][0];
        #pragma unroll
        for (int kc = 0; kc < 2; ++kc) {
            // channel pair (cs=0 at t[.], cs=1 at t[.+160]) computed packed
            const float* t = tb + (kc * 4 + hx * 2) * 160 + pc + 3;
            #define PAIR(off) (f32x2){t[off], t[(off) + 160]}
            const f32x2 L0 = PAIR(0),   Cc0 = PAIR(1),   R0 = PAIR(2);
            const f32x2 L1 = PAIR(40),  Cc1 = PAIR(41),  R1 = PAIR(42);
            const f32x2 L2 = PAIR(80),  Cc2 = PAIR(81),  R2 = PAIR(82);
            const f32x2 L3 = PAIR(120), Cc3 = PAIR(121), R3 = PAIR(122);
            #undef PAIR
            const f32x2 S0 = L0 + Cc0 + R0, S1 = L1 + Cc1 + R1;
            const f32x2 S2 = L2 + Cc2 + R2, S3 = L3 + Cc3 + R3;
            const f32x2 D0 = R0 - L0, D1 = R1 - L1;
            const f32x2 D2 = R2 - L2, D3 = R3 - L3;

            bf16x8 b0, b1;
            {   // pixel row hA (tap rows 0,1,2)
                const f32x2 T  = S1 - Cc1;
                const f32x2 F1 = S0 + S2 + T;
                const f32x2 B2 = (D0 + D2) + sp(1.4142135623730951f) * D1;
                const f32x2 B3 = (S2 - S0) + sp(0.4142135623730951f) * (Cc2 - Cc0);
                const f32x2 B4 = T - (Cc0 + Cc2);
                const f32x2 B5 = D2 - D0;
                const f32x2 F2 = sp(c1a) * B2 + sp(s1a) * B3;
                const f32x2 F3 = sp(c2a) * B4 + sp(s2a) * B5;
                b0[0]=(__bf16)Cc1.x; b0[1]=(__bf16)F1.x; b0[2]=(__bf16)F2.x; b0[3]=(__bf16)F3.x;
                b0[4]=(__bf16)Cc1.y; b0[5]=(__bf16)F1.y; b0[6]=(__bf16)F2.y; b0[7]=(__bf16)F3.y;
            }
            {   // pixel row hA+1 (tap rows 1,2,3)
                const f32x2 T  = S2 - Cc2;
                const f32x2 F1 = S1 + S3 + T;
                const f32x2 B2 = (D1 + D3) + sp(1.4142135623730951f) * D2;
                const f32x2 B3 = (S3 - S1) + sp(0.4142135623730951f) * (Cc3 - Cc1);
                const f32x2 B4 = T - (Cc1 + Cc3);
                const f32x2 B5 = D3 - D1;
                const f32x2 F2 = sp(c1b) * B2 + sp(s1b) * B3;
                const f32x2 F3 = sp(c2b) * B4 + sp(s2b) * B5;
                b1[0]=(__bf16)Cc2.x; b1[1]=(__bf16)F1.x; b1[2]=(__bf16)F2.x; b1[3]=(__bf16)F3.x;
                b1[4]=(__bf16)Cc2.y; b1[5]=(__bf16)F1.y; b1[6]=(__bf16)F2.y; b1[7]=(__bf16)F3.y;
            }
            const bf16x8 A0 = kc ? A10 : A00;
            const bf16x8 A1 = kc ? A11 : A01;
            __builtin_amdgcn_s_setprio(1);
            acc00 = __builtin_amdgcn_mfma_f32_32x32x16_bf16(A0, b0, acc00, 0, 0, 0);
            acc01 = __builtin_amdgcn_mfma_f32_32x32x16_bf16(A1, b0, acc01, 0, 0, 0);
            acc10 = __builtin_amdgcn_mfma_f32_32x32x16_bf16(A0, b1, acc10, 0, 0, 0);
            acc11 = __builtin_amdgcn_mfma_f32_32x32x16_bf16(A1, b1, acc11, 0, 0, 0);
            __builtin_amdgcn_s_setprio(0);
        }
        asm volatile("s_waitcnt lgkmcnt(0)" ::: "memory");
        __builtin_amdgcn_sched_barrier(0);
        if (c < 6) stage(c + 2);
        __builtin_amdgcn_sched_barrier(0);
    }

    // ---- epilogue: transpose each 32x32 quadrant through the dead wave-
    // private xs[W] buffer -> 16x global_store_dwordx4 (was 64 stores).
    asm volatile("s_waitcnt lgkmcnt(0)" ::: "memory");
    __builtin_amdgcn_sched_barrier(0);
    float* T = (float*)&xs[W][0][0][0][0];     // 32x32 f32 = 4KB scratch
    float* onb = out + (size_t)n * 64 * HW + (size_t)hA * WW + w0;
    const int wq = lane & 7;
    #pragma unroll
    for (int q = 0; q < 4; ++q) {
        const f32x16 aq = (q == 0) ? acc00 : (q == 1) ? acc01
                        : (q == 2) ? acc10 : acc11;
        const int rsel  = q >> 1;            // 0: row hA, 1: row hA+1
        const int ohalf = (q & 1) * 32;      // o base
        #pragma unroll
        for (int r = 0; r < 16; ++r) {
            const int ol = (r & 3) + 8 * (r >> 2) + 4 * hx;
            T[ol * 32 + pc] = aq[r];
        }
        asm volatile("s_waitcnt lgkmcnt(0)" ::: "memory");
        __builtin_amdgcn_sched_barrier(0);
        #pragma unroll
        for (int i = 0; i < 4; ++i) {
            const int olp = olp0 + i;
            f32x4 v = *(const f32x4*)&T[olp * 32 + wq * 4];
            const float bo = (q & 1) ? b4hi[i] : b4lo[i];
            v.x += bo; v.y += bo; v.z += bo; v.w += bo;
            *(f32x4*)(onb + (size_t)(ohalf + olp) * HW + rsel * WW + wq * 4) = v;
        }
        asm volatile("s_waitcnt lgkmcnt(0)" ::: "memory");
        __builtin_amdgcn_sched_barrier(0);
    }
}

extern "C" void kernel_launch(void* const* d_in, const int* in_sizes, int n_in,
                              void* d_out, int out_size, void* d_ws, size_t ws_size,
                              hipStream_t stream) {
    const float* x     = (const float*)d_in[0];
    const float* theta = (const float*)d_in[1];
    const float* wt    = (const float*)d_in[2];
    const float* bias  = (const float*)d_in[3];
    float* out = (float*)d_out;
    unsigned short* wb = (unsigned short*)d_ws;   // 32 KB bf16 weights (repacked)

    wt_repack<<<64, 256, 0, stream>>>(wt, wb);

    steered_conv_mfma<<<1024, 256, 0, stream>>>(x, theta, wb, bias, out);
}

// Round 23
// 36.630 us; speedup vs baseline: 1.3103x; 1.3103x over previous
//
#include <hip/hip_runtime.h>

// Steered 3x3 conv as per-pixel GEMM (K=256 = 64ch x 4 feats) via bf16 MFMA.
// FINAL = r16 (session best, 36.6us, verified): wave-autonomous zero-barrier
// pipeline; 1024 blocks x 4 waves; each wave owns 2 pixel rows + PRIVATE
// 10KB LDS slice (no s_barrier anywhere in the K-loop); counted per-wave
// vmcnt queue [s(c):5, w(c):4, s(c+1):5] -> vmcnt(5)/phase; packed-f32
// (v_pk) feature math over the channel pair; constants folded into repacked
// bf16 weights; bijective XCD swizzle.
// Session ledger (22 rounds): barrier-sync 42.9 / counted-vmcnt 41.9 / reg-
// prefetch 41.8 / zero-barrier 41.0 / +packed-VALU 37.3 / +4-wave-blocks
// 36.6 (THIS). Falsified levers: occupancy beyond 3 waves/SIMD (r5/r11/r17/
// r18/r20: 148-reg footprint -> spill, WRITE_SIZE 65->111..807MB), deeper
// DMA cover (r19 neutral), VMEM-instr cuts (r21 confounded, r22 hurt via
// LDS transpose bank conflicts + broken store coalescing). Wall ~2.2x the
// 16.4us HBM floor, set by per-wave latency chains at the residency cap.
// B-frag: lane l -> col = l&31 (pixel), k = 16*kcg + 8*(l>>5) + r (verified r2)
// C/D:    col = lane&31, row(o) = (r&3) + 8*(r>>2) + 4*(lane>>5)  (verified r2)

typedef __bf16 bf16x8 __attribute__((ext_vector_type(8)));
typedef float  f32x16 __attribute__((ext_vector_type(16)));
typedef float  f32x4  __attribute__((ext_vector_type(4)));
typedef float  f32x2  __attribute__((ext_vector_type(2)));
typedef unsigned int u32;
typedef const __attribute__((address_space(1))) u32* gp_t;
typedef __attribute__((address_space(3))) u32* lp_t;

#define HH 128
#define WW 128
#define HW 16384
#define CHIMG 65536          // bytes per (n,ch) plane

__device__ __forceinline__ f32x2 sp(float v) { return (f32x2){v, v}; }

// Weights f32[o][k] -> bf16, pre-scaled per feature and grouped per MFMA
// A-fragment: wb[((kcg*2+hx)*64 + o)*8 + r] = bf16(sc[k&3] * wt[o][k])
__global__ void wt_repack(const float* __restrict__ wt,
                          unsigned short* __restrict__ wb) {
    int i = blockIdx.x * 256 + threadIdx.x;   // i = o*256 + k
    int o = i >> 8, k = i & 255;
    const float sc[4] = {1.f, 0.35355339059327373f, 0.35355339059327373f, 0.5f};
    union { float f; u32 u; } v; v.f = wt[i] * sc[k & 3];
    unsigned short b = (unsigned short)((v.u + 0x7FFF + ((v.u >> 16) & 1)) >> 16);
    int kcg = k >> 4, hxx = (k >> 3) & 1, r = k & 7;
    wb[((kcg * 2 + hxx) * 64 + o) * 8 + r] = b;
}

__global__ __launch_bounds__(256, 3) void steered_conv_mfma(
    const float* __restrict__ x, const float* __restrict__ theta,
    const unsigned short* __restrict__ wb, const float* __restrict__ bias,
    float* __restrict__ out)
{
    // 4 wave-private staging slices: [wave][2 bufs][8 ch][4 rows][40 f32]
    __shared__ __attribute__((aligned(16))) float xs[4][2][8][4][40]; // 40960B

    const int tid  = threadIdx.x;
    const int W    = tid >> 6;
    const int lane = tid & 63;
    const int pc = lane & 31, hx = lane >> 5;

    // bijective XCD swizzle over 1024 blocks; block covers 4 wave-units
    const int bb   = blockIdx.x;
    const int swz  = (bb & 7) * 128 + (bb >> 3);
    const int unit = swz * 4 + W;
    const int n    = unit >> 8;
    const int rem  = unit & 255;
    const int hA   = (rem >> 2) * 2;    // wave's first pixel row (0..126)
    const int w0   = (rem & 3) * 32;
    const int w    = w0 + pc;

    // ---- per-lane DMA offsets (-1 = skip): 5 x 1024B chunks / [8ch][4r][160B] ----
    int soff[5];
    #pragma unroll
    for (int d = 0; d < 5; ++d) {
        const int i   = d * 1024 + lane * 16;
        const int ch  = i / 640;
        const int rm  = i - ch * 640;
        const int row = rm / 160;
        const int c16 = rm - row * 160;
        const int gh  = hA - 1 + row;
        const int ghc = gh < 0 ? 0 : (gh > 127 ? 127 : gh);
        int so = ch * CHIMG + ghc * 512 + w0 * 4 - 16 + c16;
        so = so < 0 ? 0 : so;
        const bool sk = (gh < 0) | (gh > 127) |
                        ((w0 == 0) & (c16 < 16)) | ((w0 == 96) & (c16 >= 144));
        soff[d] = sk ? -1 : so;
    }

    const char* xn = (const char*)x + (size_t)n * 64 * CHIMG;

    // ---- theta + harmonics (VMEM retires before the pipeline) ----
    float s1a, c1a, s1b, c1b;
    __sincosf(6.2831853071795864769f * theta[(n*HH + hA)*WW + w], &s1a, &c1a);
    __sincosf(6.2831853071795864769f * theta[(n*HH + hA+1)*WW + w], &s1b, &c1b);
    const float c2a = 2.f*c1a*c1a - 1.f, s2a = 2.f*s1a*c1a;
    const float c2b = 2.f*c1b*c1b - 1.f, s2b = 2.f*s1b*c1b;

    // ---- pre-zero own bufs when any slot will be skipped (wave-local) ----
    if (hA == 0 || hA == 126 || w0 == 0 || w0 == 96) {
        f32x4* z = (f32x4*)&xs[W][0][0][0][0];
        #pragma unroll
        for (int i = 0; i < 10; ++i)
            z[lane + i * 64] = f32x4{0.f, 0.f, 0.f, 0.f};
        asm volatile("s_waitcnt lgkmcnt(0)" ::: "memory");
    }

    auto stage = [&](int t) {                  // stages channels t*8..t*8+7
        const char* sb = xn + (size_t)(t * 8) * CHIMG;
        char* db = (char*)&xs[W][t & 1][0][0][0];
        #pragma unroll
        for (int d = 0; d < 5; ++d)
            if (soff[d] >= 0)
                __builtin_amdgcn_global_load_lds((gp_t)(sb + soff[d]),
                                                 (lp_t)(db + d * 1024), 16, 0, 0);
    };

    const unsigned short* wbl = wb + (hx * 64 + pc) * 8;
    bf16x8 wE0, wE1, wE2, wE3, wO0, wO1, wO2, wO3;

    // prologue queue: [s(0):5, w(0):4, s(1):5]
    stage(0);
    __builtin_amdgcn_sched_barrier(0);
    {
        const unsigned short* wr = wbl;
        wE0 = *(const bf16x8*)(wr);
        wE1 = *(const bf16x8*)(wr + 256);
        wE2 = *(const bf16x8*)(wr + 1024);
        wE3 = *(const bf16x8*)(wr + 1280);
    }
    __builtin_amdgcn_sched_barrier(0);
    stage(1);
    __builtin_amdgcn_sched_barrier(0);

    f32x16 acc00, acc01, acc10, acc11;
    #pragma unroll
    for (int r = 0; r < 16; ++r) { acc00[r]=0.f; acc01[r]=0.f; acc10[r]=0.f; acc11[r]=0.f; }

    #pragma unroll
    for (int c = 0; c < 8; ++c) {
        if (c == 7) asm volatile("s_waitcnt vmcnt(0)" ::: "memory");
        else        asm volatile("s_waitcnt vmcnt(5)" ::: "memory");
        __builtin_amdgcn_sched_barrier(0);
        if (c < 7) {
            const unsigned short* wr = wbl + (c + 1) * 2048;
            if ((c + 1) & 1) {
                wO0 = *(const bf16x8*)(wr);
                wO1 = *(const bf16x8*)(wr + 256);
                wO2 = *(const bf16x8*)(wr + 1024);
                wO3 = *(const bf16x8*)(wr + 1280);
            } else {
                wE0 = *(const bf16x8*)(wr);
                wE1 = *(const bf16x8*)(wr + 256);
                wE2 = *(const bf16x8*)(wr + 1024);
                wE3 = *(const bf16x8*)(wr + 1280);
            }
            __builtin_amdgcn_sched_barrier(0);
        }

        const bf16x8 A00 = (c & 1) ? wO0 : wE0;
        const bf16x8 A01 = (c & 1) ? wO1 : wE1;
        const bf16x8 A10 = (c & 1) ? wO2 : wE2;
        const bf16x8 A11 = (c & 1) ? wO3 : wE3;

        const float* tb = &xs[W][c & 1][0][0][0];
        #pragma unroll
        for (int kc = 0; kc < 2; ++kc) {
            // channel pair (cs=0 at t[.], cs=1 at t[.+160]) computed packed
            const float* t = tb + (kc * 4 + hx * 2) * 160 + pc + 3;
            #define PAIR(off) (f32x2){t[off], t[(off) + 160]}
            const f32x2 L0 = PAIR(0),   Cc0 = PAIR(1),   R0 = PAIR(2);
            const f32x2 L1 = PAIR(40),  Cc1 = PAIR(41),  R1 = PAIR(42);
            const f32x2 L2 = PAIR(80),  Cc2 = PAIR(81),  R2 = PAIR(82);
            const f32x2 L3 = PAIR(120), Cc3 = PAIR(121), R3 = PAIR(122);
            #undef PAIR
            const f32x2 S0 = L0 + Cc0 + R0, S1 = L1 + Cc1 + R1;
            const f32x2 S2 = L2 + Cc2 + R2, S3 = L3 + Cc3 + R3;
            const f32x2 D0 = R0 - L0, D1 = R1 - L1;
            const f32x2 D2 = R2 - L2, D3 = R3 - L3;

            bf16x8 b0, b1;
            {   // pixel row hA (tap rows 0,1,2)
                const f32x2 T  = S1 - Cc1;
                const f32x2 F1 = S0 + S2 + T;
                const f32x2 B2 = (D0 + D2) + sp(1.4142135623730951f) * D1;
                const f32x2 B3 = (S2 - S0) + sp(0.4142135623730951f) * (Cc2 - Cc0);
                const f32x2 B4 = T - (Cc0 + Cc2);
                const f32x2 B5 = D2 - D0;
                const f32x2 F2 = sp(c1a) * B2 + sp(s1a) * B3;
                const f32x2 F3 = sp(c2a) * B4 + sp(s2a) * B5;
                b0[0]=(__bf16)Cc1.x; b0[1]=(__bf16)F1.x; b0[2]=(__bf16)F2.x; b0[3]=(__bf16)F3.x;
                b0[4]=(__bf16)Cc1.y; b0[5]=(__bf16)F1.y; b0[6]=(__bf16)F2.y; b0[7]=(__bf16)F3.y;
            }
            {   // pixel row hA+1 (tap rows 1,2,3)
                const f32x2 T  = S2 - Cc2;
                const f32x2 F1 = S1 + S3 + T;
                const f32x2 B2 = (D1 + D3) + sp(1.4142135623730951f) * D2;
                const f32x2 B3 = (S3 - S1) + sp(0.4142135623730951f) * (Cc3 - Cc1);
                const f32x2 B4 = T - (Cc1 + Cc3);
                const f32x2 B5 = D3 - D1;
                const f32x2 F2 = sp(c1b) * B2 + sp(s1b) * B3;
                const f32x2 F3 = sp(c2b) * B4 + sp(s2b) * B5;
                b1[0]=(__bf16)Cc2.x; b1[1]=(__bf16)F1.x; b1[2]=(__bf16)F2.x; b1[3]=(__bf16)F3.x;
                b1[4]=(__bf16)Cc2.y; b1[5]=(__bf16)F1.y; b1[6]=(__bf16)F2.y; b1[7]=(__bf16)F3.y;
            }
            const bf16x8 A0 = kc ? A10 : A00;
            const bf16x8 A1 = kc ? A11 : A01;
            __builtin_amdgcn_s_setprio(1);
            acc00 = __builtin_amdgcn_mfma_f32_32x32x16_bf16(A0, b0, acc00, 0, 0, 0);
            acc01 = __builtin_amdgcn_mfma_f32_32x32x16_bf16(A1, b0, acc01, 0, 0, 0);
            acc10 = __builtin_amdgcn_mfma_f32_32x32x16_bf16(A0, b1, acc10, 0, 0, 0);
            acc11 = __builtin_amdgcn_mfma_f32_32x32x16_bf16(A1, b1, acc11, 0, 0, 0);
            __builtin_amdgcn_s_setprio(0);
        }
        asm volatile("s_waitcnt lgkmcnt(0)" ::: "memory");
        __builtin_amdgcn_sched_barrier(0);
        if (c < 6) stage(c + 2);
        __builtin_amdgcn_sched_barrier(0);
    }

    const size_t hw = (size_t)HW;
    float* op = out + (size_t)n * 64 * hw + (size_t)hA * WW + w;
    #pragma unroll
    for (int r = 0; r < 16; ++r) {
        const int o = (r & 3) + 8 * (r >> 2) + 4 * hx;
        const float bo = bias[o], bo2 = bias[o + 32];
        op[(size_t)o * hw]             = acc00[r] + bo;
        op[(size_t)(o + 32) * hw]      = acc01[r] + bo2;
        op[(size_t)o * hw + WW]        = acc10[r] + bo;
        op[(size_t)(o + 32) * hw + WW] = acc11[r] + bo2;
    }
}

extern "C" void kernel_launch(void* const* d_in, const int* in_sizes, int n_in,
                              void* d_out, int out_size, void* d_ws, size_t ws_size,
                              hipStream_t stream) {
    const float* x     = (const float*)d_in[0];
    const float* theta = (const float*)d_in[1];
    const float* wt    = (const float*)d_in[2];
    const float* bias  = (const float*)d_in[3];
    float* out = (float*)d_out;
    unsigned short* wb = (unsigned short*)d_ws;   // 32 KB bf16 weights (repacked)

    wt_repack<<<64, 256, 0, stream>>>(wt, wb);

    steered_conv_mfma<<<1024, 256, 0, stream>>>(x, theta, wb, bias, out);
}